// Round 10
// baseline (687.881 us; speedup 1.0000x reference)
//
#include <hip/hip_runtime.h>
#include <hip/hip_bf16.h>
#include <cmath>

// CapsNet forward. conv2 = split-bf16 MFMA (3-product), N=32/wave:
//  prep_all  : blocks <2592: w2 -> wstg records; blocks >=2592: conv1 -> c1g
//              (pre-split bf16 hi/lo, pre-swizzled slot order).
//  conv2_mfma: grid 512, XCD-mapped (coh=(bid&7)>>2, img=(bid>>3)*4+(bid&3));
//              256 thr / 4 waves; each wave N=32 (2 co-tiles), M=3 tiles;
//              LDS = one 50 KB c1 chunk staged via global_load_lds;
//              depth-1 B prefetch from chunk-phased L2-resident weights.
//  routing_fused: 2 images per block (shared W stream), 1280 blocks.
// ws: wstg 21.2 MB | c1g 104.9 MB | xcaps 9.4 MB = 135.5 MB

typedef float f32x4 __attribute__((ext_vector_type(4)));
typedef short s16x8 __attribute__((ext_vector_type(8)));
typedef unsigned int u32;

static __device__ __forceinline__ short f2bf(float x) {
  __hip_bfloat16 h = __float2bfloat16(x);
  return *reinterpret_cast<short*>(&h);
}
static __device__ __forceinline__ float bf2f(short s) {
  __hip_bfloat16 h;
  *reinterpret_cast<short*>(&h) = s;
  return __bfloat162float(h);
}
static __device__ __forceinline__ void stage16(const short* g, short* l) {
  __builtin_amdgcn_global_load_lds(
      (const __attribute__((address_space(1))) u32*)(const void*)g,
      (__attribute__((address_space(3))) u32*)(void*)l, 16, 0, 0);
}

// ---------------- merged prep: w2->wstg  |  conv1->c1g ----------------
__global__ __launch_bounds__(256) void prep_all(
    const float* __restrict__ w2, s16x8* __restrict__ wstg,
    const float* __restrict__ data, const float* __restrict__ w1,
    const float* __restrict__ b1, short* __restrict__ c1g) {
  if (blockIdx.x < 2592) {
    // ---- w2 split into staging records ----
    const int gid = blockIdx.x * 256 + threadIdx.x;  // 663,552 = 648*1024
    const int T = gid >> 10;
    const int s = gid & 1023;
    const int kg = s >> 8, co = s & 255;
    const int chunk = T / 81, tap = T - chunk * 81;
    const float* src = w2 + ((size_t)co * 256 + chunk * 32 + kg * 8) * 81 + tap;
    s16x8 hi, lo;
#pragma unroll
    for (int i = 0; i < 8; ++i) {
      const float x = src[i * 81];
      const short h = f2bf(x);
      hi[i] = h;
      lo[i] = f2bf(x - bf2f(h));
    }
    wstg[(size_t)T * 2048 + s] = hi;
    wstg[(size_t)T * 2048 + 1024 + s] = lo;
    return;
  }
  // ---- conv1 -> c1g (512 blocks: img*2 + yh) ----
  const int cb = blockIdx.x - 2592;
  const int img = cb >> 1;
  const int yh = cb & 1;
  const int t = threadIdx.x;
  __shared__ float simg[19 * 36];
  for (int i = t; i < 19 * 28; i += 256) {
    const int r = i / 28, c = i % 28;
    if (yh * 10 + r < 28) simg[r * 36 + c] = data[img * 784 + (yh * 10 + r) * 28 + c];
  }
  __syncthreads();
  for (int task = t; task < 2560; task += 256) {
    const int ci = task & 255;
    const int yl = task >> 8;       // 0..9
    const int y = yh * 10 + yl;
    const float* wr = w1 + ci * 81;
    float acc[20];
    const float bz = b1[ci];
#pragma unroll
    for (int x = 0; x < 20; ++x) acc[x] = bz;
#pragma unroll
    for (int ky = 0; ky < 9; ++ky) {
      float rr[28];
#pragma unroll
      for (int q = 0; q < 7; ++q)
        *(float4*)&rr[q * 4] = *(const float4*)&simg[(yl + ky) * 36 + q * 4];
#pragma unroll
      for (int kx = 0; kx < 9; ++kx) {
        const float w = wr[ky * 9 + kx];
#pragma unroll
        for (int x = 0; x < 20; ++x) acc[x] = fmaf(w, rr[x + kx], acc[x]);
      }
    }
    const int chunk = ci >> 5, cil = ci & 31, kg = cil >> 3, il = cil & 7;
    short* base = c1g + ((size_t)(img * 8 + chunk) * 400) * 64;
    const int kapy = 6 * (y >> 1);
#pragma unroll
    for (int x = 0; x < 20; ++x) {
      const int row = y * 20 + x;
      const int kap = ((x >> 1) + kapy) & 7;
      const float v = fmaxf(acc[x], 0.f);
      const short hi = f2bf(v);
      const short lo = f2bf(v - bf2f(hi));
      base[row * 64 + (((kg + kap) & 7) << 3) + il] = hi;
      base[row * 64 + (((kg + 4 + kap) & 7) << 3) + il] = lo;
    }
  }
}

// ---------------- conv2 via MFMA, N=32/wave ----------------
__global__ __launch_bounds__(256) void conv2_mfma(
    const short* __restrict__ c1g, const short* __restrict__ wstg,
    const float* __restrict__ b2, float* __restrict__ xcaps) {
  const int t = threadIdx.x;
  const int bid = blockIdx.x;        // 512
  const int xcd = bid & 7;
  const int coh = xcd >> 2;          // XCDs 0-3 -> coh 0, 4-7 -> coh 1
  const int img = (bid >> 3) * 4 + (xcd & 3);
  const int lane = t & 63;
  const int wv = t >> 6;             // 0..3
  const int r16 = lane & 15;
  const int kg = lane >> 4;

  __shared__ short c1[400 * 64];     // 51,200 B, swizzled [row][slot8][il8]

  int arow[3], kap0[3];
#pragma unroll
  for (int m = 0; m < 3; ++m) {
    int pos = m * 16 + r16;
    if (pos > 35) pos = 35;          // clamped: same-addr broadcast, discarded
    const int oy = pos / 6, ox = pos % 6;
    arow[m] = oy * 40 + ox * 2;
    kap0[m] = ox + 6 * oy;
  }
  int bOff[2], con[2];
  float bias[2];
#pragma unroll
  for (int j = 0; j < 2; ++j) {
    const int co = coh * 128 + wv * 32 + j * 16 + r16;
    con[j] = co;
    bOff[j] = kg * 256 + co;         // s16x8 slot within tap
    bias[j] = b2[co];
  }

  const f32x4 vzero = {0.f, 0.f, 0.f, 0.f};
  f32x4 acc[3][2];
#pragma unroll
  for (int m = 0; m < 3; ++m)
#pragma unroll
    for (int j = 0; j < 2; ++j) acc[m][j] = vzero;

  const s16x8* wsv = (const s16x8*)wstg;

  for (int chunk = 0; chunk < 8; ++chunk) {
    __syncthreads();  // previous chunk fully consumed
    {
      const short* src = c1g + ((size_t)(img * 8 + chunk) * 400) * 64;
      for (int c = wv; c < 50; c += 4)
        stage16(src + c * 512 + lane * 8, &c1[c * 512]);
    }
    __syncthreads();  // vmcnt drain: chunk staged

    const size_t bb = (size_t)chunk * 81 * 2048;
    s16x8 BHc[2], BLc[2];
#pragma unroll
    for (int j = 0; j < 2; ++j) {
      BHc[j] = wsv[bb + bOff[j]];
      BLc[j] = wsv[bb + bOff[j] + 1024];
    }
    for (int ky = 0; ky < 9; ++ky) {
      const int rbase = ky * 20;
      const int kapky = 6 * (ky >> 1);
#pragma unroll
      for (int kx = 0; kx < 9; ++kx) {
        const int tt = ky * 9 + kx;
        s16x8 BHn[2], BLn[2];
        if (tt < 80) {
          const size_t nb = bb + (size_t)(tt + 1) * 2048;
#pragma unroll
          for (int j = 0; j < 2; ++j) {
            BHn[j] = wsv[nb + bOff[j]];
            BLn[j] = wsv[nb + bOff[j] + 1024];
          }
        }
        s16x8 AH[3], AL[3];
#pragma unroll
        for (int m = 0; m < 3; ++m) {
          const int row = arow[m] + rbase + kx;
          const int kap = kap0[m] + (kx >> 1) + kapky;
          AH[m] = *(const s16x8*)&c1[row * 64 + (((kg + kap) & 7) << 3)];
          AL[m] = *(const s16x8*)&c1[row * 64 + (((kg + 4 + kap) & 7) << 3)];
        }
#pragma unroll
        for (int m = 0; m < 3; ++m)
#pragma unroll
          for (int j = 0; j < 2; ++j)
            acc[m][j] = __builtin_amdgcn_mfma_f32_16x16x32_bf16(AH[m], BHc[j], acc[m][j], 0, 0, 0);
#pragma unroll
        for (int m = 0; m < 3; ++m)
#pragma unroll
          for (int j = 0; j < 2; ++j)
            acc[m][j] = __builtin_amdgcn_mfma_f32_16x16x32_bf16(AL[m], BHc[j], acc[m][j], 0, 0, 0);
#pragma unroll
        for (int m = 0; m < 3; ++m)
#pragma unroll
          for (int j = 0; j < 2; ++j)
            acc[m][j] = __builtin_amdgcn_mfma_f32_16x16x32_bf16(AH[m], BLc[j], acc[m][j], 0, 0, 0);
#pragma unroll
        for (int j = 0; j < 2; ++j) { BHc[j] = BHn[j]; BLc[j] = BLn[j]; }
      }
    }
  }

  // store: D col = r16 (co), row = kg*4 + reg (pos)
#pragma unroll
  for (int m = 0; m < 3; ++m) {
#pragma unroll
    for (int jj = 0; jj < 4; ++jj) {
      const int pos = m * 16 + kg * 4 + jj;
      if (pos < 36) {
#pragma unroll
        for (int j = 0; j < 2; ++j) {
          const int co = con[j];
          const int n = (co & 31) * 36 + pos;
          xcaps[((size_t)img * 1152 + n) * 8 + (co >> 5)] = acc[m][j][jj] + bias[j];
        }
      }
    }
  }
}

// ---------------- fused u_hat + routing: block per (o, image-pair) ----------------
__global__ __launch_bounds__(256) void routing_fused(const float* __restrict__ xcaps,
                                                     const float* __restrict__ W,
                                                     float* __restrict__ out) {
  const int o = blockIdx.x >> 7;     // 0..9
  const int bp = blockIdx.x & 127;   // image pair
  const int b0 = bp * 2, b1 = b0 + 1;
  const int t = threadIdx.x;
  const int k = t & 15, ng = t >> 4;
  __shared__ float xs0[1152 * 8];
  __shared__ float xs1[1152 * 8];
  __shared__ double redA[256], redB[256], redC[256], redD[256];
  __shared__ float s0s[16], s1s[16];
  __shared__ float sv0, sv1;
  __shared__ double f0, f1;

  {
    const float4* src0 = (const float4*)(xcaps + (size_t)b0 * 9216);
    const float4* src1 = (const float4*)(xcaps + (size_t)b1 * 9216);
    float4* d0 = (float4*)xs0;
    float4* d1 = (float4*)xs1;
    for (int i = t; i < 2304; i += 256) { d0[i] = src0[i]; d1[i] = src1[i]; }
  }
  __syncthreads();

  const int n0 = ng * 72;
  float u0[72], u1[72];
  const float* wp = W + ((size_t)(n0 * 10 + o) * 16 + k) * 8;
#pragma unroll
  for (int i = 0; i < 72; ++i) {
    const float* wq = wp + (size_t)i * 1280;
    const float4 wa = *(const float4*)wq;
    const float4 wb = *(const float4*)(wq + 4);
    const float4 xa0 = *(const float4*)&xs0[(n0 + i) * 8];
    const float4 xb0 = *(const float4*)&xs0[(n0 + i) * 8 + 4];
    const float4 xa1 = *(const float4*)&xs1[(n0 + i) * 8];
    const float4 xb1 = *(const float4*)&xs1[(n0 + i) * 8 + 4];
    float s0 = wa.x * xa0.x + wa.y * xa0.y + wa.z * xa0.z + wa.w * xa0.w
             + wb.x * xb0.x + wb.y * xb0.y + wb.z * xb0.z + wb.w * xb0.w;
    float s1 = wa.x * xa1.x + wa.y * xa1.y + wa.z * xa1.z + wa.w * xa1.w
             + wb.x * xb1.x + wb.y * xb1.y + wb.z * xb1.z + wb.w * xb1.w;
    u0[i] = s0;
    u1[i] = s1;
  }

  // ---- pass 1: uniform c = 1/1152 ----
  {
    double S0 = 0.0, S1 = 0.0;
#pragma unroll
    for (int i = 0; i < 72; ++i) { S0 += (double)u0[i]; S1 += (double)u1[i]; }
    redA[t] = S0; redB[t] = S1;
  }
  __syncthreads();
  if (t < 16) {
    double t0 = 0.0, t1 = 0.0;
#pragma unroll
    for (int g = 0; g < 16; ++g) { t0 += redA[g * 16 + t]; t1 += redB[g * 16 + t]; }
    s0s[t] = (float)(t0 * (double)(1.0f / 1152.0f));
    s1s[t] = (float)(t1 * (double)(1.0f / 1152.0f));
  }
  __syncthreads();
  if (t == 0) {
    double sn = 0.0;
#pragma unroll
    for (int kk = 0; kk < 16; ++kk) sn += (double)s0s[kk] * (double)s0s[kk];
    double f = sn / ((1.0 + sn) * sqrt(sn));
    double sv = 0.0;
#pragma unroll
    for (int kk = 0; kk < 16; ++kk) sv += (double)s0s[kk] * f;
    sv0 = (float)sv;
    sn = 0.0;
#pragma unroll
    for (int kk = 0; kk < 16; ++kk) sn += (double)s1s[kk] * (double)s1s[kk];
    f = sn / ((1.0 + sn) * sqrt(sn));
    sv = 0.0;
#pragma unroll
    for (int kk = 0; kk < 16; ++kk) sv += (double)s1s[kk] * f;
    sv1 = (float)sv;
  }
  __syncthreads();
  const float v10 = sv0, v11 = sv1;

  // ---- pass 2: logits u*sv1 ----
  {
    double E0 = 0.0, EU0 = 0.0, E1 = 0.0, EU1 = 0.0;
#pragma unroll
    for (int i = 0; i < 72; ++i) {
      const float e0 = expf(u0[i] * v10);
      E0 += (double)e0;
      EU0 += (double)e0 * (double)u0[i];
      const float e1 = expf(u1[i] * v11);
      E1 += (double)e1;
      EU1 += (double)e1 * (double)u1[i];
    }
    redA[t] = E0; redB[t] = EU0; redC[t] = E1; redD[t] = EU1;
  }
  __syncthreads();
  if (t < 16) {
    double e0 = 0.0, s0 = 0.0, e1 = 0.0, s1 = 0.0;
#pragma unroll
    for (int g = 0; g < 16; ++g) {
      e0 += redA[g * 16 + t]; s0 += redB[g * 16 + t];
      e1 += redC[g * 16 + t]; s1 += redD[g * 16 + t];
    }
    s0s[t] = (float)(s0 / e0);
    s1s[t] = (float)(s1 / e1);
  }
  __syncthreads();
  if (t == 0) {
    double sn = 0.0;
#pragma unroll
    for (int kk = 0; kk < 16; ++kk) sn += (double)s0s[kk] * (double)s0s[kk];
    double f = sn / ((1.0 + sn) * sqrt(sn));
    double sv = 0.0;
#pragma unroll
    for (int kk = 0; kk < 16; ++kk) sv += (double)s0s[kk] * f;
    sv0 = v10 + (float)sv;
    sn = 0.0;
#pragma unroll
    for (int kk = 0; kk < 16; ++kk) sn += (double)s1s[kk] * (double)s1s[kk];
    f = sn / ((1.0 + sn) * sqrt(sn));
    sv = 0.0;
#pragma unroll
    for (int kk = 0; kk < 16; ++kk) sv += (double)s1s[kk] * f;
    sv1 = v11 + (float)sv;
  }
  __syncthreads();
  const float v20 = sv0, v21 = sv1;

  // ---- pass 3 -> output ----
  {
    double E0 = 0.0, EU0 = 0.0, E1 = 0.0, EU1 = 0.0;
#pragma unroll
    for (int i = 0; i < 72; ++i) {
      const float e0 = expf(u0[i] * v20);
      E0 += (double)e0;
      EU0 += (double)e0 * (double)u0[i];
      const float e1 = expf(u1[i] * v21);
      E1 += (double)e1;
      EU1 += (double)e1 * (double)u1[i];
    }
    redA[t] = E0; redB[t] = EU0; redC[t] = E1; redD[t] = EU1;
  }
  __syncthreads();
  if (t < 16) {
    double e0 = 0.0, s0 = 0.0, e1 = 0.0, s1 = 0.0;
#pragma unroll
    for (int g = 0; g < 16; ++g) {
      e0 += redA[g * 16 + t]; s0 += redB[g * 16 + t];
      e1 += redC[g * 16 + t]; s1 += redD[g * 16 + t];
    }
    s0s[t] = (float)(s0 / e0);
    s1s[t] = (float)(s1 / e1);
  }
  __syncthreads();
  if (t == 0) {
    double sn = 0.0;
#pragma unroll
    for (int kk = 0; kk < 16; ++kk) sn += (double)s0s[kk] * (double)s0s[kk];
    f0 = sn / ((1.0 + sn) * sqrt(sn));
    sn = 0.0;
#pragma unroll
    for (int kk = 0; kk < 16; ++kk) sn += (double)s1s[kk] * (double)s1s[kk];
    f1 = sn / ((1.0 + sn) * sqrt(sn));
  }
  __syncthreads();
  if (t < 16) {
    out[b0 * 160 + o * 16 + t] = (float)((double)s0s[t] * f0);
    out[b1 * 160 + o * 16 + t] = (float)((double)s1s[t] * f1);
  }
}

extern "C" void kernel_launch(void* const* d_in, const int* in_sizes, int n_in,
                              void* d_out, int out_size, void* d_ws, size_t ws_size,
                              hipStream_t stream) {
  const float* data = (const float*)d_in[0];
  const float* w1   = (const float*)d_in[1];
  const float* b1   = (const float*)d_in[2];
  const float* w2   = (const float*)d_in[3];
  const float* b2   = (const float*)d_in[4];
  const float* W    = (const float*)d_in[5];
  float* out = (float*)d_out;

  short* wstg  = (short*)d_ws;               // 10,616,832 shorts (21.2 MB)
  short* c1g   = wstg + 10616832;            // 52,428,800 shorts (104.9 MB)
  float* xcaps = (float*)(c1g + 52428800);   //  2,359,296 floats ( 9.4 MB)

  prep_all<<<3104, 256, 0, stream>>>(w2, (s16x8*)wstg, data, w1, b1, c1g);
  conv2_mfma<<<512, 256, 0, stream>>>(c1g, wstg, b2, xcaps);
  routing_fused<<<1280, 256, 0, stream>>>(xcaps, W, out);
}